// Round 1
// baseline (5460.826 us; speedup 1.0000x reference)
//
#include <hip/hip_runtime.h>

// LatentGuidedEdgeDecoder — round 4: kill redundant weight streaming.
// R3 (1 row/block) was L2-BW-bound: every block re-read all 3.67MB of weights
// -> 240GB L2 traffic ~= 7.0ms ~= measured 7669us. This version:
//   * 64 rows/block (1024 blocks): 64x weight-traffic reduction.
//   * lane = row (64 lanes), wave = 64-col slice: weight addresses are
//     wave-uniform (scalarizable s_load), 64 reg-accumulators/thread,
//     each LDS activation read feeds 64 FMAs.
//   * activations staged in LDS [64][260] f32 (stride 260 = 4 mod 32 ->
//     conflict-optimal ds_read_b128; 260*4 = 16B-aligned rows).
//   * whole forward fused; fusion GEMM accumulated incrementally
//     (edge part right after edge) so only 2 big LDS buffers needed.
//   * LN per row = lane-local sum + 4-wave LDS exchange (row==lane).
// Dtype runtime dispatch preserved (f32 vs bf16 world). bf16 world converts
// weights once/call to f32 in ws when ws_size permits (guarded fallback).

typedef __bf16 bf16;
#define HD 256
#define RPB 64
#define AST 260
#define CONV_OFF 32768
#define CONV_FLOATS 957064
#define WS_NEED (CONV_OFF + CONV_FLOATS * 4)

__device__ __forceinline__ float bf2f(unsigned short u) {
  union { unsigned int i; float f; } c; c.i = ((unsigned)u) << 16; return c.f;
}
__device__ __forceinline__ float4 ld4c(const float* p) { return *(const float4*)p; }
__device__ __forceinline__ float4 ld4c(const bf16* p) {
  ushort4 u = *(const ushort4*)p;
  return make_float4(bf2f(u.x), bf2f(u.y), bf2f(u.z), bf2f(u.w));
}
template <class T>
__device__ __forceinline__ float ld(const T* __restrict__ p) { return (float)*p; }

// ---------------- dtype detector ----------------
__global__ void k_detect(const unsigned int* __restrict__ wds, int* __restrict__ flag, int nw) {
  __shared__ int sRed[4];
  int t = threadIdx.x;
  int cnt = 0;
  for (int i = t; i < nw; i += 256) {
    unsigned e = (wds[i] >> 7) & 0xFFu;
    cnt += (e >= 110u && e <= 140u) ? 1 : 0;
  }
#pragma unroll
  for (int m = 1; m < 64; m <<= 1) cnt += __shfl_xor(cnt, m);
  if ((t & 63) == 0) sRed[t >> 6] = cnt;
  __syncthreads();
  if (t == 0) flag[0] = (sRed[0] + sRed[1] + sRed[2] + sRed[3] > nw / 2) ? 1 : 0;
}

// ---------------- attention collapse precompute ----------------
template <class T, int WANT>
__global__ void k_cvo_a(const int* __restrict__ flag, const T* __restrict__ Wc,
                        const T* __restrict__ Wv, const T* __restrict__ bc,
                        const T* __restrict__ bv, float* __restrict__ tmp) {
  if (*flag != WANT) return;
  int i = blockIdx.x;
  int m = threadIdx.x;
  float s = 0.f;
  if (i < 8) {
    for (int u = 0; u < 256; ++u) s += ld(Wc + i * 256 + u) * ld(Wv + (size_t)u * 256 + m);
  } else {
    for (int u = 0; u < 256; ++u) s += ld(bc + u) * ld(Wv + (size_t)u * 256 + m);
    s += ld(bv + m);
  }
  tmp[i * 256 + m] = s;
}

template <class T, int WANT>
__global__ void k_cvo_b(const int* __restrict__ flag, const float* __restrict__ tmp,
                        const T* __restrict__ Wo, const T* __restrict__ bo,
                        float* __restrict__ Wcvo, float* __restrict__ bcvo) {
  if (*flag != WANT) return;
  int i = blockIdx.x;
  int m = threadIdx.x;
  float s = 0.f;
  const float* tr = tmp + i * 256;
  for (int u = 0; u < 256; ++u) s += tr[u] * ld(Wo + (size_t)u * 256 + m);
  if (i < 8) Wcvo[i * 256 + m] = s;
  else       bcvo[m] = s + ld(bo + m);
}

// ---------------- bf16 -> f32 weight conversion (bf16 world only) ----------------
__global__ void k_conv(const int* __restrict__ flag,
                       const bf16* s0, const bf16* s1, const bf16* s2, const bf16* s3,
                       const bf16* s4, const bf16* s5, const bf16* s6, const bf16* s7,
                       const bf16* s8, const bf16* s9, const bf16* s10, const bf16* s11,
                       const bf16* s12, const bf16* s13, const bf16* s14, const bf16* s15,
                       const bf16* s16, const bf16* s17, const bf16* s18,
                       float* __restrict__ dst) {
  if (*flag != 1) return;
  const bf16* srcs[19] = {s0,s1,s2,s3,s4,s5,s6,s7,s8,s9,s10,s11,s12,s13,s14,s15,s16,s17,s18};
  const int offs[20] = {0,131072,131328,131584,131840,132096,132352,134400,527616,528384,
                        724992,725760,922368,922624,922880,923136,955904,956032,957056,957064};
  int t = blockIdx.x * blockDim.x + threadIdx.x;
  int np = gridDim.x * blockDim.x;
#pragma unroll
  for (int seg = 0; seg < 19; ++seg) {
    const unsigned short* s = (const unsigned short*)srcs[seg];
    float* d = dst + offs[seg];
    int n = offs[seg + 1] - offs[seg];
    for (int i = t; i < n; i += np) d[i] = bf2f(s[i]);
  }
}

// ---------------- GEMM micro-kernels: acc[j] += sum_k x[k] * W[k][cb+j] ----------------
template <int K, int LDW, class XT, class WT>
__device__ __forceinline__ void gemm64(float* __restrict__ acc, const XT* __restrict__ x,
                                       const WT* __restrict__ wb) {
#pragma unroll 2
  for (int k = 0; k < K; k += 4) {
    float4 xv = ld4c(x + k);
#pragma unroll
    for (int kk = 0; kk < 4; ++kk) {
      float xs = (kk == 0) ? xv.x : (kk == 1) ? xv.y : (kk == 2) ? xv.z : xv.w;
      const WT* wr = wb + (size_t)(k + kk) * LDW;
#pragma unroll
      for (int j = 0; j < 16; ++j) {
        float4 wv = ld4c(wr + j * 4);
        acc[j*4+0] = fmaf(xs, wv.x, acc[j*4+0]);
        acc[j*4+1] = fmaf(xs, wv.y, acc[j*4+1]);
        acc[j*4+2] = fmaf(xs, wv.z, acc[j*4+2]);
        acc[j*4+3] = fmaf(xs, wv.w, acc[j*4+3]);
      }
    }
  }
}

template <int K, int LDW, class XT, class WT>
__device__ __forceinline__ void gemm32(float* __restrict__ acc, const XT* __restrict__ x,
                                       const WT* __restrict__ wb) {
#pragma unroll 2
  for (int k = 0; k < K; k += 4) {
    float4 xv = ld4c(x + k);
#pragma unroll
    for (int kk = 0; kk < 4; ++kk) {
      float xs = (kk == 0) ? xv.x : (kk == 1) ? xv.y : (kk == 2) ? xv.z : xv.w;
      const WT* wr = wb + (size_t)(k + kk) * LDW;
#pragma unroll
      for (int j = 0; j < 8; ++j) {
        float4 wv = ld4c(wr + j * 4);
        acc[j*4+0] = fmaf(xs, wv.x, acc[j*4+0]);
        acc[j*4+1] = fmaf(xs, wv.y, acc[j*4+1]);
        acc[j*4+2] = fmaf(xs, wv.z, acc[j*4+2]);
        acc[j*4+3] = fmaf(xs, wv.w, acc[j*4+3]);
      }
    }
  }
}

template <class WT>
__device__ __forceinline__ void ld64v(float* d, const WT* p) {
#pragma unroll
  for (int j = 0; j < 16; ++j) {
    float4 v = ld4c(p + j * 4);
    d[j*4+0] = v.x; d[j*4+1] = v.y; d[j*4+2] = v.z; d[j*4+3] = v.w;
  }
}
template <class WT>
__device__ __forceinline__ void add64v(float* d, const WT* p) {
#pragma unroll
  for (int j = 0; j < 16; ++j) {
    float4 v = ld4c(p + j * 4);
    d[j*4+0] += v.x; d[j*4+1] += v.y; d[j*4+2] += v.z; d[j*4+3] += v.w;
  }
}
__device__ __forceinline__ void st64v(float* p, const float* a) {
#pragma unroll
  for (int j = 0; j < 16; ++j)
    *(float4*)(p + j * 4) = make_float4(a[j*4+0], a[j*4+1], a[j*4+2], a[j*4+3]);
}

template <bool RELU, class WT>
__device__ __forceinline__ void ln_apply(float* acc, float mean, float rstd,
                                         const WT* g, const WT* b) {
#pragma unroll
  for (int j = 0; j < 16; ++j) {
    float4 gv = ld4c(g + j * 4), bv = ld4c(b + j * 4);
    acc[j*4+0] = (acc[j*4+0] - mean) * rstd * gv.x + bv.x;
    acc[j*4+1] = (acc[j*4+1] - mean) * rstd * gv.y + bv.y;
    acc[j*4+2] = (acc[j*4+2] - mean) * rstd * gv.z + bv.z;
    acc[j*4+3] = (acc[j*4+3] - mean) * rstd * gv.w + bv.w;
    if (RELU) {
      acc[j*4+0] = fmaxf(acc[j*4+0], 0.f);
      acc[j*4+1] = fmaxf(acc[j*4+1], 0.f);
      acc[j*4+2] = fmaxf(acc[j*4+2], 0.f);
      acc[j*4+3] = fmaxf(acc[j*4+3], 0.f);
    }
  }
}

// per-row LN stats: lane-local sums + cross-wave LDS exchange (row == lane)
__device__ __forceinline__ void ln_stats(const float* acc, int w, int l, float* red,
                                         float& mean, float& rstd) {
  float s = 0.f, q = 0.f;
#pragma unroll
  for (int j = 0; j < 64; ++j) { s += acc[j]; q += acc[j] * acc[j]; }
  __syncthreads();                       // previous red use done
  red[(w * 64 + l) * 2]     = s;
  red[(w * 64 + l) * 2 + 1] = q;
  __syncthreads();
  s = red[l*2] + red[(64+l)*2] + red[(128+l)*2] + red[(192+l)*2];
  q = red[l*2+1] + red[(64+l)*2+1] + red[(128+l)*2+1] + red[(192+l)*2+1];
  mean = s * (1.f / 256.f);
  float var = q * (1.f / 256.f) - mean * mean;
  rstd = rsqrtf(var + 1e-5f);
}

template <class T>
__device__ __forceinline__ void stage256(float* dst, const T* __restrict__ src, int nv, int t) {
#pragma unroll
  for (int ii = 0; ii < 16; ++ii) {
    int i = t + ii * 256;
    int r = i >> 6, c4 = i & 63;
    float4 v = make_float4(0.f, 0.f, 0.f, 0.f);
    if (r < nv) v = ld4c(src + (size_t)r * HD + c4 * 4);
    *(float4*)(dst + r * AST + c4 * 4) = v;
  }
}

// ---------------- the fused row kernel: 64 rows/block ----------------
template <class T, class WT, int WANT>
__global__ __launch_bounds__(256, 1) void k_row(
    const int* __restrict__ flag, int Brows,
    const T* __restrict__ node_i, const T* __restrict__ node_j,
    const T* __restrict__ latent, const T* __restrict__ hin,
    const int* __restrict__ tok,
    const WT* __restrict__ We, const WT* __restrict__ be,
    const WT* __restrict__ ge, const WT* __restrict__ bee,
    const WT* __restrict__ gn, const WT* __restrict__ bn,
    const WT* __restrict__ emb,
    const WT* __restrict__ W_ih, const WT* __restrict__ b_ih,
    const WT* __restrict__ W_hh, const WT* __restrict__ b_hh,
    const WT* __restrict__ Wf, const WT* __restrict__ bfb,
    const WT* __restrict__ gf, const WT* __restrict__ bff,
    const WT* __restrict__ W1, const WT* __restrict__ b1,
    const WT* __restrict__ W2, const WT* __restrict__ b2,
    const float* __restrict__ Wcvo, const float* __restrict__ bcvo,
    T* __restrict__ outL, T* __restrict__ outNH) {
  if (*flag != WANT) return;
  extern __shared__ float sm[];
  float* A   = sm;                    // [64][AST]
  float* Bb  = sm + 64 * AST;         // [64][AST]
  float* red = sm + 2 * 64 * AST;     // 512 f32
  float* sc  = red + 512;             // 2048 f32 (latent stage / head partials)
  int* tokS  = (int*)(sc + 2048);     // 64 ints

  const int t = threadIdx.x;
  const int w = __builtin_amdgcn_readfirstlane(t >> 6);  // wave id: uniform col base
  const int l = t & 63;                                  // lane == local row
  const int row0 = blockIdx.x * RPB;
  int nv = Brows - row0; if (nv > RPB) nv = RPB;
  const int cb = w * 64;

  if (t < 64) tokS[t] = (t < nv) ? tok[row0 + t] : 0;
  stage256(A, node_i + (size_t)row0 * HD, nv, t);
  __syncthreads();

  // ---- edge = relu(LN([node_i|node_j] @ We + be)) ----
  float acc[64];
  ld64v(acc, be + cb);
  gemm64<256, 256>(acc, A + l * AST, We + cb);
  __syncthreads();                    // A(node_i) reads done
  stage256(A, node_j + (size_t)row0 * HD, nv, t);
  __syncthreads();
  gemm64<256, 256>(acc, A + l * AST, We + (size_t)256 * 256 + cb);
  float mean, rstd;
  ln_stats(acc, w, l, red, mean, rstd);
  ln_apply<true>(acc, mean, rstd, ge + cb, bee + cb);
  st64v(Bb + l * AST + cb, acc);      // Bb = edge
  __syncthreads();

  // ---- fusion accumulator: edge part first (so edge never needs a 3rd buffer) ----
  float fac[64];
  ld64v(fac, bfb + cb);
  gemm64<256, 256>(fac, Bb + l * AST, Wf + cb);

  // ---- attended = LN(latent @ Wcvo + bcvo) ----
#pragma unroll
  for (int ii = 0; ii < 2; ++ii) {
    int i = t + ii * 256;
    int r = i >> 3, c = i & 7;
    sc[i] = (r < nv) ? ld(latent + (size_t)(row0 + r) * 8 + c) : 0.f;
  }
  __syncthreads();                    // also: Bb(edge) fusion reads done (all threads)
  ld64v(acc, bcvo + cb);
  gemm64<8, 256>(acc, sc + l * 8, Wcvo + cb);
  ln_stats(acc, w, l, red, mean, rstd);
  ln_apply<false>(acc, mean, rstd, gn + cb, bn + cb);
  st64v(A + l * AST + cb, acc);       // A = attended
  __syncthreads();

  gemm64<256, 256>(fac, A + l * AST, Wf + (size_t)256 * 256 + cb);  // fusion: att part

  stage256(Bb, hin + (size_t)row0 * HD, nv, t);                     // Bb = hin
  __syncthreads();

  const int tk = tokS[l];
  const WT* embr = emb + (size_t)tk * HD;   // 8 rows only: L1-resident

  // ---- GRU r gate ----
  ld64v(acc, b_ih + cb); add64v(acc, b_hh + cb);
  gemm64<256, 768>(acc, A + l * AST, W_ih + cb);
  gemm64<256, 768>(acc, embr, W_ih + (size_t)256 * 768 + cb);
  gemm64<256, 768>(acc, Bb + l * AST, W_hh + cb);
  float rg[64];
#pragma unroll
  for (int j = 0; j < 64; ++j) rg[j] = 1.f / (1.f + expf(-acc[j]));

  // ---- ghn; rg <- r * ghn ----
  ld64v(acc, b_hh + 512 + cb);
  gemm64<256, 768>(acc, Bb + l * AST, W_hh + 512 + cb);
#pragma unroll
  for (int j = 0; j < 64; ++j) rg[j] *= acc[j];

  // ---- gin; rg <- n = tanh(gin + r*ghn) ----
  ld64v(acc, b_ih + 512 + cb);
  gemm64<256, 768>(acc, A + l * AST, W_ih + 512 + cb);
  gemm64<256, 768>(acc, embr, W_ih + (size_t)256 * 768 + 512 + cb);
#pragma unroll
  for (int j = 0; j < 64; ++j) rg[j] = tanhf(acc[j] + rg[j]);

  // ---- z gate; newh ----
  ld64v(acc, b_ih + 256 + cb); add64v(acc, b_hh + 256 + cb);
  gemm64<256, 768>(acc, A + l * AST, W_ih + 256 + cb);
  gemm64<256, 768>(acc, embr, W_ih + (size_t)256 * 768 + 256 + cb);
  gemm64<256, 768>(acc, Bb + l * AST, W_hh + 256 + cb);
  __syncthreads();                    // all Bb(hin)/A(att) GEMM reads done
#pragma unroll
  for (int j4 = 0; j4 < 16; ++j4) {
    float4 hv = ld4c(Bb + l * AST + cb + j4 * 4);
    float z0 = 1.f / (1.f + expf(-acc[j4*4+0]));
    float z1 = 1.f / (1.f + expf(-acc[j4*4+1]));
    float z2 = 1.f / (1.f + expf(-acc[j4*4+2]));
    float z3 = 1.f / (1.f + expf(-acc[j4*4+3]));
    acc[j4*4+0] = (1.f - z0) * rg[j4*4+0] + z0 * hv.x;
    acc[j4*4+1] = (1.f - z1) * rg[j4*4+1] + z1 * hv.y;
    acc[j4*4+2] = (1.f - z2) * rg[j4*4+2] + z2 * hv.z;
    acc[j4*4+3] = (1.f - z3) * rg[j4*4+3] + z3 * hv.w;
  }
  st64v(Bb + l * AST + cb, acc);      // Bb = newh
  __syncthreads();

  for (int i = t; i < nv * HD; i += 256) {
    int r = i >> 8, c = i & 255;
    outNH[(size_t)(row0 + r) * HD + c] = (T)Bb[r * AST + c];
  }

  // ---- fusion: newh part; fused = relu(LN(fac)) ----
  gemm64<256, 256>(fac, Bb + l * AST, Wf + (size_t)512 * 256 + cb);
  ln_stats(fac, w, l, red, mean, rstd);
  ln_apply<true>(fac, mean, rstd, gf + cb, bff + cb);
  st64v(A + l * AST + cb, fac);       // A = fused
  __syncthreads();

  // ---- head: relu(fused @ W1 + b1) @ W2 + b2 ----
  float h1[32];
#pragma unroll
  for (int j = 0; j < 8; ++j) {
    float4 v = ld4c(b1 + w * 32 + j * 4);
    h1[j*4+0] = v.x; h1[j*4+1] = v.y; h1[j*4+2] = v.z; h1[j*4+3] = v.w;
  }
  gemm32<256, 128>(h1, A + l * AST, W1 + w * 32);
  float part[8];
#pragma unroll
  for (int o = 0; o < 8; ++o) part[o] = 0.f;
#pragma unroll
  for (int kk = 0; kk < 32; ++kk) {
    float hval = fmaxf(h1[kk], 0.f);
    const WT* w2r = W2 + (size_t)(w * 32 + kk) * 8;
    float4 a0 = ld4c(w2r), a1 = ld4c(w2r + 4);
    part[0] = fmaf(hval, a0.x, part[0]);
    part[1] = fmaf(hval, a0.y, part[1]);
    part[2] = fmaf(hval, a0.z, part[2]);
    part[3] = fmaf(hval, a0.w, part[3]);
    part[4] = fmaf(hval, a1.x, part[4]);
    part[5] = fmaf(hval, a1.y, part[5]);
    part[6] = fmaf(hval, a1.z, part[6]);
    part[7] = fmaf(hval, a1.w, part[7]);
  }
#pragma unroll
  for (int o = 0; o < 8; ++o) sc[(w * 64 + l) * 8 + o] = part[o];
  __syncthreads();
  if (w == 0 && l < nv) {
#pragma unroll
    for (int o = 0; o < 8; ++o) {
      float lg = ld(b2 + o) + sc[l*8+o] + sc[(64+l)*8+o] + sc[(128+l)*8+o] + sc[(192+l)*8+o];
      outL[(size_t)(row0 + l) * 8 + o] = (T)lg;
    }
  }
}

// ---------------- launch ----------------
extern "C" void kernel_launch(void* const* d_in, const int* in_sizes, int n_in,
                              void* d_out, int out_size, void* d_ws, size_t ws_size,
                              hipStream_t stream) {
  char* ws = (char*)d_ws;
  const int B = in_sizes[0] / HD;
  const int nblk = (B + RPB - 1) / RPB;
  int* flag = (int*)ws;
  float* tmpcv = (float*)(ws + 1024);
  float* Wcvo  = (float*)(ws + 16384);
  float* bcvo  = (float*)(ws + 24576);
  float* conv  = (float*)(ws + CONV_OFF);

  int nw = B * 128; if (nw > 16384) nw = 16384;
  k_detect<<<1, 256, 0, stream>>>((const unsigned int*)d_in[0], flag, nw);

  const size_t SMEM = (size_t)(2 * 64 * AST + 512 + 2048) * 4 + 64 * 4;

  // ---- f32 world ----
  {
    auto P = [&](int i) { return (const float*)d_in[i]; };
    k_cvo_a<float, 0><<<9, 256, 0, stream>>>(flag, P(9), P(15), P(10), P(16), tmpcv);
    k_cvo_b<float, 0><<<9, 256, 0, stream>>>(flag, tmpcv, P(17), P(18), Wcvo, bcvo);
    (void)hipFuncSetAttribute(reinterpret_cast<const void*>(&k_row<float, float, 0>),
                              hipFuncAttributeMaxDynamicSharedMemorySize, (int)SMEM);
    k_row<float, float, 0><<<nblk, 256, SMEM, stream>>>(
        flag, B, P(0), P(1), P(2), P(3), (const int*)d_in[4],
        P(5), P(6), P(7), P(8), P(19), P(20), P(21),
        P(22), P(23), P(24), P(25), P(26), P(27), P(28), P(29),
        P(30), P(31), P(32), P(33), Wcvo, bcvo,
        (float*)d_out, (float*)d_out + (size_t)B * 8);
  }
  // ---- bf16 world ----
  {
    auto P = [&](int i) { return (const bf16*)d_in[i]; };
    k_cvo_a<bf16, 1><<<9, 256, 0, stream>>>(flag, P(9), P(15), P(10), P(16), tmpcv);
    k_cvo_b<bf16, 1><<<9, 256, 0, stream>>>(flag, tmpcv, P(17), P(18), Wcvo, bcvo);
    bf16* oL = (bf16*)d_out;
    if (ws_size >= (size_t)WS_NEED) {
      k_conv<<<512, 256, 0, stream>>>(flag,
          P(5), P(6), P(7), P(8), P(19), P(20), P(21),
          P(22), P(23), P(24), P(25), P(26), P(27), P(28), P(29),
          P(30), P(31), P(32), P(33), conv);
      const float* C = conv;
      (void)hipFuncSetAttribute(reinterpret_cast<const void*>(&k_row<bf16, float, 1>),
                                hipFuncAttributeMaxDynamicSharedMemorySize, (int)SMEM);
      k_row<bf16, float, 1><<<nblk, 256, SMEM, stream>>>(
          flag, B, P(0), P(1), P(2), P(3), (const int*)d_in[4],
          C + 0, C + 131072, C + 131328, C + 131584, C + 131840, C + 132096, C + 132352,
          C + 134400, C + 527616, C + 528384, C + 724992, C + 725760, C + 922368,
          C + 922624, C + 922880, C + 923136, C + 955904, C + 956032, C + 957056,
          Wcvo, bcvo, oL, oL + (size_t)B * 8);
    } else {
      (void)hipFuncSetAttribute(reinterpret_cast<const void*>(&k_row<bf16, bf16, 1>),
                                hipFuncAttributeMaxDynamicSharedMemorySize, (int)SMEM);
      k_row<bf16, bf16, 1><<<nblk, 256, SMEM, stream>>>(
          flag, B, P(0), P(1), P(2), P(3), (const int*)d_in[4],
          P(5), P(6), P(7), P(8), P(19), P(20), P(21),
          P(22), P(23), P(24), P(25), P(26), P(27), P(28), P(29),
          P(30), P(31), P(32), P(33), Wcvo, bcvo, oL, oL + (size_t)B * 8);
    }
  }
}

// Round 2
// 2283.797 us; speedup vs baseline: 2.3911x; 2.3911x over previous
//
#include <hip/hip_runtime.h>

// LatentGuidedEdgeDecoder — round 5: fix occupancy (1 wave/SIMD -> 4 waves/SIMD).
// R4 counters: VALUBusy 17.8%, Occupancy 12.2% (= 4 waves/CU: 143KB LDS -> 1 block/CU,
// block had only 4 waves). Latency-bound on uniform-address weight loads with zero TLP.
// R5: same dataflow/LDS (64 rows/block), but 1024 threads = 16 waves x 16-col slices:
//   * 4 waves/SIMD from the one resident block -> L2 latency hidden by TLP.
//   * per-thread acc 64 -> 16 regs; __launch_bounds__(1024,4) caps VGPR at 128
//     so all 16 waves are resident.
//   * weight traffic per block unchanged (each wave streams its own 16-col slice).
//   * LN stats: lane-local sums + 16-wave LDS exchange (lane == row).
//   * head partials (16w x 64r x 8) reuse Bb (dead after newh consumed).
// Dtype runtime dispatch preserved (f32 vs bf16 world); bf16 world converts weights
// once/call to f32 in ws when ws_size permits.

typedef __bf16 bf16;
#define HD 256
#define RPB 64
#define AST 260
#define TPB 1024
#define CONV_OFF 32768
#define CONV_FLOATS 957064
#define WS_NEED (CONV_OFF + CONV_FLOATS * 4)

__device__ __forceinline__ float bf2f(unsigned short u) {
  union { unsigned int i; float f; } c; c.i = ((unsigned)u) << 16; return c.f;
}
__device__ __forceinline__ float4 ld4c(const float* p) { return *(const float4*)p; }
__device__ __forceinline__ float4 ld4c(const bf16* p) {
  ushort4 u = *(const ushort4*)p;
  return make_float4(bf2f(u.x), bf2f(u.y), bf2f(u.z), bf2f(u.w));
}
template <class T>
__device__ __forceinline__ float ld(const T* __restrict__ p) { return (float)*p; }

// ---------------- dtype detector ----------------
__global__ void k_detect(const unsigned int* __restrict__ wds, int* __restrict__ flag, int nw) {
  __shared__ int sRed[4];
  int t = threadIdx.x;
  int cnt = 0;
  for (int i = t; i < nw; i += 256) {
    unsigned e = (wds[i] >> 7) & 0xFFu;
    cnt += (e >= 110u && e <= 140u) ? 1 : 0;
  }
#pragma unroll
  for (int m = 1; m < 64; m <<= 1) cnt += __shfl_xor(cnt, m);
  if ((t & 63) == 0) sRed[t >> 6] = cnt;
  __syncthreads();
  if (t == 0) flag[0] = (sRed[0] + sRed[1] + sRed[2] + sRed[3] > nw / 2) ? 1 : 0;
}

// ---------------- attention collapse precompute ----------------
template <class T, int WANT>
__global__ void k_cvo_a(const int* __restrict__ flag, const T* __restrict__ Wc,
                        const T* __restrict__ Wv, const T* __restrict__ bc,
                        const T* __restrict__ bv, float* __restrict__ tmp) {
  if (*flag != WANT) return;
  int i = blockIdx.x;
  int m = threadIdx.x;
  float s = 0.f;
  if (i < 8) {
    for (int u = 0; u < 256; ++u) s += ld(Wc + i * 256 + u) * ld(Wv + (size_t)u * 256 + m);
  } else {
    for (int u = 0; u < 256; ++u) s += ld(bc + u) * ld(Wv + (size_t)u * 256 + m);
    s += ld(bv + m);
  }
  tmp[i * 256 + m] = s;
}

template <class T, int WANT>
__global__ void k_cvo_b(const int* __restrict__ flag, const float* __restrict__ tmp,
                        const T* __restrict__ Wo, const T* __restrict__ bo,
                        float* __restrict__ Wcvo, float* __restrict__ bcvo) {
  if (*flag != WANT) return;
  int i = blockIdx.x;
  int m = threadIdx.x;
  float s = 0.f;
  const float* tr = tmp + i * 256;
  for (int u = 0; u < 256; ++u) s += tr[u] * ld(Wo + (size_t)u * 256 + m);
  if (i < 8) Wcvo[i * 256 + m] = s;
  else       bcvo[m] = s + ld(bo + m);
}

// ---------------- bf16 -> f32 weight conversion (bf16 world only) ----------------
__global__ void k_conv(const int* __restrict__ flag,
                       const bf16* s0, const bf16* s1, const bf16* s2, const bf16* s3,
                       const bf16* s4, const bf16* s5, const bf16* s6, const bf16* s7,
                       const bf16* s8, const bf16* s9, const bf16* s10, const bf16* s11,
                       const bf16* s12, const bf16* s13, const bf16* s14, const bf16* s15,
                       const bf16* s16, const bf16* s17, const bf16* s18,
                       float* __restrict__ dst) {
  if (*flag != 1) return;
  const bf16* srcs[19] = {s0,s1,s2,s3,s4,s5,s6,s7,s8,s9,s10,s11,s12,s13,s14,s15,s16,s17,s18};
  const int offs[20] = {0,131072,131328,131584,131840,132096,132352,134400,527616,528384,
                        724992,725760,922368,922624,922880,923136,955904,956032,957056,957064};
  int t = blockIdx.x * blockDim.x + threadIdx.x;
  int np = gridDim.x * blockDim.x;
#pragma unroll
  for (int seg = 0; seg < 19; ++seg) {
    const unsigned short* s = (const unsigned short*)srcs[seg];
    float* d = dst + offs[seg];
    int n = offs[seg + 1] - offs[seg];
    for (int i = t; i < n; i += np) d[i] = bf2f(s[i]);
  }
}

// ---------------- GEMM micro-kernels ----------------
template <int K, int LDW, class XT, class WT>
__device__ __forceinline__ void gemm16(float* __restrict__ acc, const XT* __restrict__ x,
                                       const WT* __restrict__ wb) {
#pragma unroll 2
  for (int k = 0; k < K; k += 4) {
    float4 xv = ld4c(x + k);
#pragma unroll
    for (int kk = 0; kk < 4; ++kk) {
      float xs = (kk == 0) ? xv.x : (kk == 1) ? xv.y : (kk == 2) ? xv.z : xv.w;
      const WT* wr = wb + (size_t)(k + kk) * LDW;
#pragma unroll
      for (int j = 0; j < 4; ++j) {
        float4 wv = ld4c(wr + j * 4);
        acc[j*4+0] = fmaf(xs, wv.x, acc[j*4+0]);
        acc[j*4+1] = fmaf(xs, wv.y, acc[j*4+1]);
        acc[j*4+2] = fmaf(xs, wv.z, acc[j*4+2]);
        acc[j*4+3] = fmaf(xs, wv.w, acc[j*4+3]);
      }
    }
  }
}

template <int K, int LDW, class XT, class WT>
__device__ __forceinline__ void gemm8(float* __restrict__ acc, const XT* __restrict__ x,
                                      const WT* __restrict__ wb) {
#pragma unroll 2
  for (int k = 0; k < K; k += 4) {
    float4 xv = ld4c(x + k);
#pragma unroll
    for (int kk = 0; kk < 4; ++kk) {
      float xs = (kk == 0) ? xv.x : (kk == 1) ? xv.y : (kk == 2) ? xv.z : xv.w;
      const WT* wr = wb + (size_t)(k + kk) * LDW;
#pragma unroll
      for (int j = 0; j < 2; ++j) {
        float4 wv = ld4c(wr + j * 4);
        acc[j*4+0] = fmaf(xs, wv.x, acc[j*4+0]);
        acc[j*4+1] = fmaf(xs, wv.y, acc[j*4+1]);
        acc[j*4+2] = fmaf(xs, wv.z, acc[j*4+2]);
        acc[j*4+3] = fmaf(xs, wv.w, acc[j*4+3]);
      }
    }
  }
}

template <class WT>
__device__ __forceinline__ void ld16v(float* d, const WT* p) {
#pragma unroll
  for (int j = 0; j < 4; ++j) {
    float4 v = ld4c(p + j * 4);
    d[j*4+0] = v.x; d[j*4+1] = v.y; d[j*4+2] = v.z; d[j*4+3] = v.w;
  }
}
template <class WT>
__device__ __forceinline__ void add16v(float* d, const WT* p) {
#pragma unroll
  for (int j = 0; j < 4; ++j) {
    float4 v = ld4c(p + j * 4);
    d[j*4+0] += v.x; d[j*4+1] += v.y; d[j*4+2] += v.z; d[j*4+3] += v.w;
  }
}
__device__ __forceinline__ void st16v(float* p, const float* a) {
#pragma unroll
  for (int j = 0; j < 4; ++j)
    *(float4*)(p + j * 4) = make_float4(a[j*4+0], a[j*4+1], a[j*4+2], a[j*4+3]);
}

template <bool RELU, class WT>
__device__ __forceinline__ void ln_apply16(float* acc, float mean, float rstd,
                                           const WT* g, const WT* b) {
#pragma unroll
  for (int j = 0; j < 4; ++j) {
    float4 gv = ld4c(g + j * 4), bv = ld4c(b + j * 4);
    acc[j*4+0] = (acc[j*4+0] - mean) * rstd * gv.x + bv.x;
    acc[j*4+1] = (acc[j*4+1] - mean) * rstd * gv.y + bv.y;
    acc[j*4+2] = (acc[j*4+2] - mean) * rstd * gv.z + bv.z;
    acc[j*4+3] = (acc[j*4+3] - mean) * rstd * gv.w + bv.w;
    if (RELU) {
      acc[j*4+0] = fmaxf(acc[j*4+0], 0.f);
      acc[j*4+1] = fmaxf(acc[j*4+1], 0.f);
      acc[j*4+2] = fmaxf(acc[j*4+2], 0.f);
      acc[j*4+3] = fmaxf(acc[j*4+3], 0.f);
    }
  }
}

__device__ __forceinline__ void ln_stats16(const float* acc, int w, int l, float* red,
                                           float& mean, float& rstd) {
  float s = 0.f, q = 0.f;
#pragma unroll
  for (int j = 0; j < 16; ++j) { s += acc[j]; q += acc[j] * acc[j]; }
  __syncthreads();                       // previous red/LDS use done
  *(float2*)(red + (w * 64 + l) * 2) = make_float2(s, q);
  __syncthreads();
  s = 0.f; q = 0.f;
#pragma unroll
  for (int ww = 0; ww < 16; ++ww) {
    float2 v = *(const float2*)(red + (ww * 64 + l) * 2);
    s += v.x; q += v.y;
  }
  mean = s * (1.f / 256.f);
  float var = q * (1.f / 256.f) - mean * mean;
  rstd = rsqrtf(var + 1e-5f);
}

template <class T>
__device__ __forceinline__ void stage256(float* dst, const T* __restrict__ src, int nv, int t) {
#pragma unroll
  for (int ii = 0; ii < 4; ++ii) {
    int i = t + ii * TPB;
    int r = i >> 6, c4 = i & 63;
    float4 v = make_float4(0.f, 0.f, 0.f, 0.f);
    if (r < nv) v = ld4c(src + (size_t)r * HD + c4 * 4);
    *(float4*)(dst + r * AST + c4 * 4) = v;
  }
}

// ---------------- the fused row kernel: 64 rows/block, 16 waves x 16 cols ----------------
template <class T, class WT, int WANT>
__global__ __launch_bounds__(TPB, 4) void k_row(
    const int* __restrict__ flag, int Brows,
    const T* __restrict__ node_i, const T* __restrict__ node_j,
    const T* __restrict__ latent, const T* __restrict__ hin,
    const int* __restrict__ tok,
    const WT* __restrict__ We, const WT* __restrict__ be,
    const WT* __restrict__ ge, const WT* __restrict__ bee,
    const WT* __restrict__ gn, const WT* __restrict__ bn,
    const WT* __restrict__ emb,
    const WT* __restrict__ W_ih, const WT* __restrict__ b_ih,
    const WT* __restrict__ W_hh, const WT* __restrict__ b_hh,
    const WT* __restrict__ Wf, const WT* __restrict__ bfb,
    const WT* __restrict__ gf, const WT* __restrict__ bff,
    const WT* __restrict__ W1, const WT* __restrict__ b1,
    const WT* __restrict__ W2, const WT* __restrict__ b2,
    const float* __restrict__ Wcvo, const float* __restrict__ bcvo,
    T* __restrict__ outL, T* __restrict__ outNH) {
  if (*flag != WANT) return;
  extern __shared__ float sm[];
  float* A   = sm;                    // [64][AST]
  float* Bb  = sm + 64 * AST;         // [64][AST]  (also head-partial scratch)
  float* red = sm + 2 * 64 * AST;     // 16*64*2 = 2048 f32
  float* sc  = red + 2048;            // 512 f32 (latent stage)
  int* tokS  = (int*)(sc + 512);      // 64 ints

  const int t = threadIdx.x;
  const int w = __builtin_amdgcn_readfirstlane(t >> 6);  // wave id 0..15 (uniform)
  const int l = t & 63;                                  // lane == local row
  const int row0 = blockIdx.x * RPB;
  int nv = Brows - row0; if (nv > RPB) nv = RPB;
  const int cb = w * 16;              // this wave's output-column base

  if (t < 64) tokS[t] = (t < nv) ? tok[row0 + t] : 0;
  stage256(A, node_i + (size_t)row0 * HD, nv, t);
  __syncthreads();

  // ---- edge = relu(LN([node_i|node_j] @ We + be)) ----
  float acc[16];
  ld16v(acc, be + cb);
  gemm16<256, 256>(acc, A + l * AST, We + cb);
  __syncthreads();                    // A(node_i) reads done
  stage256(A, node_j + (size_t)row0 * HD, nv, t);
  __syncthreads();
  gemm16<256, 256>(acc, A + l * AST, We + (size_t)256 * 256 + cb);
  float mean, rstd;
  ln_stats16(acc, w, l, red, mean, rstd);
  ln_apply16<true>(acc, mean, rstd, ge + cb, bee + cb);
  st16v(Bb + l * AST + cb, acc);      // Bb = edge
  __syncthreads();

  // ---- fusion accumulator: edge part first ----
  float fac[16];
  ld16v(fac, bfb + cb);
  gemm16<256, 256>(fac, Bb + l * AST, Wf + cb);

  // ---- attended = LN(latent @ Wcvo + bcvo) ----
  if (t < 512) {
    int r = t >> 3, c = t & 7;
    sc[t] = (r < nv) ? ld(latent + (size_t)(row0 + r) * 8 + c) : 0.f;
  }
  __syncthreads();                    // sc ready; also: Bb(edge) fusion reads done
  ld16v(acc, bcvo + cb);
  gemm16<8, 256>(acc, sc + l * 8, Wcvo + cb);
  ln_stats16(acc, w, l, red, mean, rstd);
  ln_apply16<false>(acc, mean, rstd, gn + cb, bn + cb);
  st16v(A + l * AST + cb, acc);       // A = attended
  __syncthreads();

  gemm16<256, 256>(fac, A + l * AST, Wf + (size_t)256 * 256 + cb);  // fusion: att part

  stage256(Bb, hin + (size_t)row0 * HD, nv, t);                     // Bb = hin
  __syncthreads();

  const int tk = tokS[l];
  const WT* embr = emb + (size_t)tk * HD;   // 8 rows only: cache-resident

  // ---- GRU r gate ----
  ld16v(acc, b_ih + cb); add16v(acc, b_hh + cb);
  gemm16<256, 768>(acc, A + l * AST, W_ih + cb);
  gemm16<256, 768>(acc, embr, W_ih + (size_t)256 * 768 + cb);
  gemm16<256, 768>(acc, Bb + l * AST, W_hh + cb);
  float rg[16];
#pragma unroll
  for (int j = 0; j < 16; ++j) rg[j] = 1.f / (1.f + expf(-acc[j]));

  // ---- ghn; rg <- r * ghn ----
  ld16v(acc, b_hh + 512 + cb);
  gemm16<256, 768>(acc, Bb + l * AST, W_hh + 512 + cb);
#pragma unroll
  for (int j = 0; j < 16; ++j) rg[j] *= acc[j];

  // ---- gin; rg <- n = tanh(gin + r*ghn) ----
  ld16v(acc, b_ih + 512 + cb);
  gemm16<256, 768>(acc, A + l * AST, W_ih + 512 + cb);
  gemm16<256, 768>(acc, embr, W_ih + (size_t)256 * 768 + 512 + cb);
#pragma unroll
  for (int j = 0; j < 16; ++j) rg[j] = tanhf(acc[j] + rg[j]);

  // ---- z gate; newh ----
  ld16v(acc, b_ih + 256 + cb); add16v(acc, b_hh + 256 + cb);
  gemm16<256, 768>(acc, A + l * AST, W_ih + 256 + cb);
  gemm16<256, 768>(acc, embr, W_ih + (size_t)256 * 768 + 256 + cb);
  gemm16<256, 768>(acc, Bb + l * AST, W_hh + 256 + cb);
  __syncthreads();                    // all Bb(hin)/A(att) GEMM reads done
#pragma unroll
  for (int j4 = 0; j4 < 4; ++j4) {
    float4 hv = ld4c(Bb + l * AST + cb + j4 * 4);
    float z0 = 1.f / (1.f + expf(-acc[j4*4+0]));
    float z1 = 1.f / (1.f + expf(-acc[j4*4+1]));
    float z2 = 1.f / (1.f + expf(-acc[j4*4+2]));
    float z3 = 1.f / (1.f + expf(-acc[j4*4+3]));
    acc[j4*4+0] = (1.f - z0) * rg[j4*4+0] + z0 * hv.x;
    acc[j4*4+1] = (1.f - z1) * rg[j4*4+1] + z1 * hv.y;
    acc[j4*4+2] = (1.f - z2) * rg[j4*4+2] + z2 * hv.z;
    acc[j4*4+3] = (1.f - z3) * rg[j4*4+3] + z3 * hv.w;
  }
  st16v(Bb + l * AST + cb, acc);      // Bb = newh
  __syncthreads();

  for (int i = t; i < nv * HD; i += TPB) {
    int r = i >> 8, c = i & 255;
    outNH[(size_t)(row0 + r) * HD + c] = (T)Bb[r * AST + c];
  }

  // ---- fusion: newh part; fused = relu(LN(fac)) ----
  gemm16<256, 256>(fac, Bb + l * AST, Wf + (size_t)512 * 256 + cb);
  ln_stats16(fac, w, l, red, mean, rstd);
  ln_apply16<true>(fac, mean, rstd, gf + cb, bff + cb);
  st16v(A + l * AST + cb, fac);       // A = fused
  __syncthreads();

  // ---- head: relu(fused @ W1 + b1) @ W2 + b2 ----
  float h1[8];
  {
    float4 v0 = ld4c(b1 + w * 8), v1 = ld4c(b1 + w * 8 + 4);
    h1[0]=v0.x; h1[1]=v0.y; h1[2]=v0.z; h1[3]=v0.w;
    h1[4]=v1.x; h1[5]=v1.y; h1[6]=v1.z; h1[7]=v1.w;
  }
  gemm8<256, 128>(h1, A + l * AST, W1 + w * 8);
  float part[8];
#pragma unroll
  for (int o = 0; o < 8; ++o) part[o] = 0.f;
#pragma unroll
  for (int kk = 0; kk < 8; ++kk) {
    float hval = fmaxf(h1[kk], 0.f);
    const WT* w2r = W2 + (size_t)(w * 8 + kk) * 8;
    float4 a0 = ld4c(w2r), a1 = ld4c(w2r + 4);
    part[0] = fmaf(hval, a0.x, part[0]);
    part[1] = fmaf(hval, a0.y, part[1]);
    part[2] = fmaf(hval, a0.z, part[2]);
    part[3] = fmaf(hval, a0.w, part[3]);
    part[4] = fmaf(hval, a1.x, part[4]);
    part[5] = fmaf(hval, a1.y, part[5]);
    part[6] = fmaf(hval, a1.z, part[6]);
    part[7] = fmaf(hval, a1.w, part[7]);
  }
  float* hp = Bb;                     // reuse Bb for 16*64*8 partials (newh consumed)
  *(float4*)(hp + (w * 64 + l) * 8)     = make_float4(part[0], part[1], part[2], part[3]);
  *(float4*)(hp + (w * 64 + l) * 8 + 4) = make_float4(part[4], part[5], part[6], part[7]);
  __syncthreads();
  if (w == 0 && l < nv) {
#pragma unroll
    for (int o = 0; o < 8; ++o) {
      float lg = ld(b2 + o);
#pragma unroll
      for (int ww = 0; ww < 16; ++ww) lg += hp[(ww * 64 + l) * 8 + o];
      outL[(size_t)(row0 + l) * 8 + o] = (T)lg;
    }
  }
}

// ---------------- launch ----------------
extern "C" void kernel_launch(void* const* d_in, const int* in_sizes, int n_in,
                              void* d_out, int out_size, void* d_ws, size_t ws_size,
                              hipStream_t stream) {
  char* ws = (char*)d_ws;
  const int B = in_sizes[0] / HD;
  const int nblk = (B + RPB - 1) / RPB;
  int* flag = (int*)ws;
  float* tmpcv = (float*)(ws + 1024);
  float* Wcvo  = (float*)(ws + 16384);
  float* bcvo  = (float*)(ws + 24576);
  float* conv  = (float*)(ws + CONV_OFF);

  int nw = B * 128; if (nw > 16384) nw = 16384;
  k_detect<<<1, 256, 0, stream>>>((const unsigned int*)d_in[0], flag, nw);

  const size_t SMEM = (size_t)(2 * 64 * AST + 2048 + 512) * 4 + 64 * 4;

  // ---- f32 world ----
  {
    auto P = [&](int i) { return (const float*)d_in[i]; };
    k_cvo_a<float, 0><<<9, 256, 0, stream>>>(flag, P(9), P(15), P(10), P(16), tmpcv);
    k_cvo_b<float, 0><<<9, 256, 0, stream>>>(flag, tmpcv, P(17), P(18), Wcvo, bcvo);
    (void)hipFuncSetAttribute(reinterpret_cast<const void*>(&k_row<float, float, 0>),
                              hipFuncAttributeMaxDynamicSharedMemorySize, (int)SMEM);
    k_row<float, float, 0><<<nblk, TPB, SMEM, stream>>>(
        flag, B, P(0), P(1), P(2), P(3), (const int*)d_in[4],
        P(5), P(6), P(7), P(8), P(19), P(20), P(21),
        P(22), P(23), P(24), P(25), P(26), P(27), P(28), P(29),
        P(30), P(31), P(32), P(33), Wcvo, bcvo,
        (float*)d_out, (float*)d_out + (size_t)B * 8);
  }
  // ---- bf16 world ----
  {
    auto P = [&](int i) { return (const bf16*)d_in[i]; };
    k_cvo_a<bf16, 1><<<9, 256, 0, stream>>>(flag, P(9), P(15), P(10), P(16), tmpcv);
    k_cvo_b<bf16, 1><<<9, 256, 0, stream>>>(flag, tmpcv, P(17), P(18), Wcvo, bcvo);
    bf16* oL = (bf16*)d_out;
    if (ws_size >= (size_t)WS_NEED) {
      k_conv<<<512, 256, 0, stream>>>(flag,
          P(5), P(6), P(7), P(8), P(19), P(20), P(21),
          P(22), P(23), P(24), P(25), P(26), P(27), P(28), P(29),
          P(30), P(31), P(32), P(33), conv);
      const float* C = conv;
      (void)hipFuncSetAttribute(reinterpret_cast<const void*>(&k_row<bf16, float, 1>),
                                hipFuncAttributeMaxDynamicSharedMemorySize, (int)SMEM);
      k_row<bf16, float, 1><<<nblk, TPB, SMEM, stream>>>(
          flag, B, P(0), P(1), P(2), P(3), (const int*)d_in[4],
          C + 0, C + 131072, C + 131328, C + 131584, C + 131840, C + 132096, C + 132352,
          C + 134400, C + 527616, C + 528384, C + 724992, C + 725760, C + 922368,
          C + 922624, C + 922880, C + 923136, C + 955904, C + 956032, C + 957056,
          Wcvo, bcvo, oL, oL + (size_t)B * 8);
    } else {
      (void)hipFuncSetAttribute(reinterpret_cast<const void*>(&k_row<bf16, bf16, 1>),
                                hipFuncAttributeMaxDynamicSharedMemorySize, (int)SMEM);
      k_row<bf16, bf16, 1><<<nblk, TPB, SMEM, stream>>>(
          flag, B, P(0), P(1), P(2), P(3), (const int*)d_in[4],
          P(5), P(6), P(7), P(8), P(19), P(20), P(21),
          P(22), P(23), P(24), P(25), P(26), P(27), P(28), P(29),
          P(30), P(31), P(32), P(33), Wcvo, bcvo, oL, oL + (size_t)B * 8);
    }
  }
}